// Round 9
// baseline (148.680 us; speedup 1.0000x reference)
//
#include <hip/hip_runtime.h>
#include <math.h>

#ifndef M_PI
#define M_PI 3.14159265358979323846
#endif

#define T 2048
#define EDGE 256
#define TT 1536            // trimmed timesteps
#define PHA_N 50
#define AMP_N 30
#define NBANDS 80
#define NBINS 18
#define NBC 16             // B*C = 2*8
#define FMAX 768           // forward DFT bins stored [0, FMAX); max needed bin = 634
#define NCH 16             // t-chunks for forward DFT
#define CHLEN (T / NCH)    // 128
#define QS 4               // t-quarters for mi_part
#define QT (TT / QS)       // 384
#define ASCALE 262144.0f   // 2^18 fixed-point scale for amp quantization

// Inclusive frequency-bin range [fl, fh] for a band, replicating the
// reference's float32 band edges vs exact quarter-Hz freq grid.
__device__ __forceinline__ void band_range(int band, int* fl, int* fh) {
    double lo, hi;
    if (band < PHA_N) {
        double mid = 2.0 + (double)band * (18.0 / 49.0);   // linspace(2,20,50)
        lo = (double)(float)(mid * 0.75);
        hi = (double)(float)(mid * 1.25);
    } else {
        int j = band - PHA_N;
        double mid = 60.0 + (double)j * (81.0 / 29.0);     // linspace(60,141,30)
        lo = (double)(float)(mid * 0.875);
        hi = (double)(float)(mid * 1.125);
    }
    int l = (int)ceil(lo * 4.0);     // freq = 0.25*f ; f >= 4*lo
    int h = (int)floor(hi * 4.0);    // f <= 4*hi
    if (l < 1) l = 1;
    if (h > FMAX - 1) h = FMAX - 1;
    *fl = l; *fh = h;
}

// Kernel A: chunked forward DFT partials. Two independent 64-step oscillator
// chains per thread; Xp layout ch-slowest for coalesced writes.
__global__ void dft_kernel(const float* __restrict__ x, double* __restrict__ Xp) {
    __shared__ float xs[CHLEN];
    const int bc = blockIdx.x;
    const int fb = blockIdx.y;
    const int ch = blockIdx.z;
    const int tid = threadIdx.x;
    const int t0 = ch * CHLEN;
    if (tid < CHLEN) xs[tid] = x[bc * T + t0 + tid];
    __syncthreads();
    const int f = fb * 256 + tid;
    const double om = 2.0 * M_PI / (double)T;
    double s, c;
    sincos(om * (double)(f & (T - 1)), &s, &c);
    const double wR = c, wI = -s;                       // e^{-i om f}
    double curR[2], curI[2], accR[2], accI[2];
    #pragma unroll
    for (int h = 0; h < 2; ++h) {
        sincos(om * (double)((f * (t0 + h * 64)) & (T - 1)), &s, &c);
        curR[h] = c; curI[h] = -s;                      // e^{-i om f (t0+64h)}
        accR[h] = 0.0; accI[h] = 0.0;
    }
    #pragma unroll 2
    for (int t = 0; t < 64; ++t) {
        #pragma unroll
        for (int h = 0; h < 2; ++h) {
            double v = (double)xs[t + h * 64];
            accR[h] += v * curR[h];
            accI[h] += v * curI[h];
            double nR = curR[h] * wR - curI[h] * wI;
            double nI = curR[h] * wI + curI[h] * wR;
            curR[h] = nR; curI[h] = nI;
        }
    }
    const size_t o = (size_t)((ch * NBC + bc) * FMAX + f) * 2;
    Xp[o + 0] = accR[0] + accR[1];
    Xp[o + 1] = accI[0] + accI[1];
}

// Kernel A2: reduce NCH chunk partials -> Xf[bc][f]. Coalesced.
__global__ void reduce_kernel(const double* __restrict__ Xp, double* __restrict__ Xf) {
    const int gid = blockIdx.x * 256 + threadIdx.x;   // 0..12287 = bc*FMAX+f
    double r = 0.0, im = 0.0;
    #pragma unroll
    for (int c = 0; c < NCH; ++c) {
        r  += Xp[((size_t)c * NBC * FMAX + gid) * 2 + 0];
        im += Xp[((size_t)c * NBC * FMAX + gid) * 2 + 1];
    }
    Xf[2 * gid + 0] = r;
    Xf[2 * gid + 1] = im;
}

// Kernel B: per (bc, band, t-half) analytic-signal synthesis.
// Phase bands fp64 (bin decision); amp bands fp32, stored as u32 fixed-point
// (amp * 2^18, round-nearest) for mi_part's integer accumulation.
#define NJ 3
__global__ void band_kernel(const double* __restrict__ Xf,
                            unsigned char* __restrict__ idx_buf,
                            unsigned int* __restrict__ ampu_buf) {
    __shared__ double sXr[164];
    __shared__ double sXi[164];
    const int bc = blockIdx.x;
    const int band = (NBANDS - 1) - blockIdx.y;   // biggest bands first
    const int half = blockIdx.z;
    const int tid = threadIdx.x;
    int fl, fh;
    band_range(band, &fl, &fh);
    const int nb = fh - fl + 1;
    const double om = 2.0 * M_PI / (double)T;

    if (band < PHA_N) {
        // ---------- fp64 phase path ----------
        for (int i = tid; i < nb; i += 256) {
            sXr[i] = Xf[(size_t)(bc * FMAX + fl + i) * 2 + 0];
            sXi[i] = Xf[(size_t)(bc * FMAX + fl + i) * 2 + 1];
        }
        __syncthreads();
        double curR[NJ], curI[NJ], wR[NJ], wI[NJ], accR[NJ], accI[NJ];
        #pragma unroll
        for (int j = 0; j < NJ; ++j) {
            const int t = tid + j * 256 + half * 768 + EDGE;
            double s, c;
            sincos(om * (double)((fl * t) & (T - 1)), &s, &c);
            curR[j] = c; curI[j] = s;          // e^{+i om fl t}
            sincos(om * (double)(t & (T - 1)), &s, &c);
            wR[j] = c; wI[j] = s;              // e^{+i om t}
            accR[j] = 0.0; accI[j] = 0.0;
        }
        #pragma unroll 2
        for (int i = 0; i < nb; ++i) {
            const double Xr = sXr[i], Xi = sXi[i];   // broadcast read
            #pragma unroll
            for (int j = 0; j < NJ; ++j) {
                accR[j] += Xr * curR[j] - Xi * curI[j];
                accI[j] += Xr * curI[j] + Xi * curR[j];
                double nR = curR[j] * wR[j] - curI[j] * wI[j];
                double nI = curR[j] * wI[j] + curI[j] * wR[j];
                curR[j] = nR; curI[j] = nI;
            }
        }
        const double width = 2.0 * M_PI / (double)NBINS;
        #pragma unroll
        for (int j = 0; j < NJ; ++j) {
            const int trel = tid + j * 256 + half * 768;
            double pha = atan2(accI[j], accR[j]);        // (-pi, pi]
            int b = (int)floor((pha + M_PI) / width);
            if (b < 0) b = 0;
            if (b > NBINS - 1) b = NBINS - 1;
            idx_buf[(size_t)(bc * PHA_N + band) * TT + trel] = (unsigned char)b;
        }
    } else {
        // ---------- fp32 amplitude path ----------
        float* fXr = (float*)sXr;
        float* fXi = (float*)sXi;
        for (int i = tid; i < nb; i += 256) {
            fXr[i] = (float)Xf[(size_t)(bc * FMAX + fl + i) * 2 + 0];
            fXi[i] = (float)Xf[(size_t)(bc * FMAX + fl + i) * 2 + 1];
        }
        __syncthreads();
        float curR[NJ], curI[NJ], wRf[NJ], wIf[NJ], accR[NJ], accI[NJ];
        #pragma unroll
        for (int j = 0; j < NJ; ++j) {
            const int t = tid + j * 256 + half * 768 + EDGE;
            double s, c;
            sincos(om * (double)((fl * t) & (T - 1)), &s, &c);
            curR[j] = (float)c; curI[j] = (float)s;
            sincos(om * (double)(t & (T - 1)), &s, &c);
            wRf[j] = (float)c; wIf[j] = (float)s;
            accR[j] = 0.0f; accI[j] = 0.0f;
        }
        #pragma unroll 2
        for (int i = 0; i < nb; ++i) {
            const float Xr = fXr[i], Xi = fXi[i];
            #pragma unroll
            for (int j = 0; j < NJ; ++j) {
                accR[j] += Xr * curR[j] - Xi * curI[j];
                accI[j] += Xr * curI[j] + Xi * curR[j];
                float nR = curR[j] * wRf[j] - curI[j] * wIf[j];
                float nI = curR[j] * wIf[j] + curI[j] * wRf[j];
                curR[j] = nR; curI[j] = nI;
            }
        }
        #pragma unroll
        for (int j = 0; j < NJ; ++j) {
            const int trel = tid + j * 256 + half * 768;
            float amp = sqrtf(accR[j] * accR[j] + accI[j] * accI[j]) * (2.0f / (float)T);
            ampu_buf[(size_t)(bc * AMP_N + (band - PHA_N)) * TT + trel] =
                (unsigned int)(amp * ASCALE + 0.5f);
        }
    }
}

// Kernel C1: per (bc, phase band p, t-quarter): counts + bin sums via PLAIN
// u32 read-modify-write on per-thread private padded LDS rows.
// Measured lesson ladder: float LDS atomicAdd -> CAS loop (R5, 204 us);
// u32 LDS atomicAdd -> native but ~46 cyc/wave-atomic scattered (R8, 44 us);
// plain b32 read+write ~6 cyc each, 2-way conflicts free -> this version.
#define PK 19   // padded row stride
#define NROW 31 // 30 amp bands + counts row
__global__ void mi_part(const unsigned char* __restrict__ idx_buf,
                        const unsigned int* __restrict__ ampu_buf,
                        unsigned int* __restrict__ Sums) {
    __shared__ unsigned int part[NROW * 8 * PK];  // [row=a*8+g][k], u32 fixed-point
    __shared__ unsigned int sidx_s[QT / 4];       // 96 packed idx words
    const int blk = blockIdx.x;               // bc*50 + p
    const int q = blockIdx.y;                 // t-quarter
    const int bc = blk / PHA_N;
    const int p = blk % PHA_N;
    const int tid = threadIdx.x;

    for (int i = tid; i < NROW * 8 * PK; i += 256) part[i] = 0u;
    if (tid < QT / 4)
        sidx_s[tid] = ((const unsigned int*)(idx_buf + (size_t)(bc * PHA_N + p) * TT + q * QT))[tid];
    __syncthreads();

    if (tid < NROW * 8) {
        const int a = tid >> 3;     // 0..30 (30 == counts row)
        const int g = tid & 7;      // contiguous 48-t chunk per thread
        const uint4* ap = (const uint4*)(ampu_buf + (size_t)(bc * AMP_N + a) * TT + q * QT) + g * 12;
        unsigned int* myp = part + tid * PK;  // private row: no races, plain RMW
        #pragma unroll
        for (int it = 0; it < 12; ++it) {
            const unsigned int pk = sidx_s[g * 12 + it];   // LDS broadcast
            uint4 v;
            if (a < AMP_N) v = ap[it];
            else { v.x = 1u; v.y = 1u; v.z = 1u; v.w = 1u; }
            myp[pk & 0xff]         += v.x;
            myp[(pk >> 8) & 0xff]  += v.y;
            myp[(pk >> 16) & 0xff] += v.z;
            myp[(pk >> 24) & 0xff] += v.w;
        }
    }
    __syncthreads();

    for (int i = tid; i < NROW * NBINS; i += 256) {
        const int row = i / NBINS, k = i - row * NBINS;
        unsigned int s = 0u;
        #pragma unroll
        for (int g = 0; g < 8; ++g) s += part[(row * 8 + g) * PK + k];
        atomicAdd(&Sums[((size_t)blk * NROW + row) * NBINS + k], s);   // global u32
    }
}

// Kernel C2: MI from Sums. One thread per (pair, amp band).
__global__ void mi_final(const unsigned int* __restrict__ Sums, float* __restrict__ out) {
    const int gid = blockIdx.x * 256 + threadIdx.x;
    if (gid >= NBC * PHA_N * AMP_N) return;
    const int pair = gid / AMP_N;
    const int a = gid - pair * AMP_N;
    const unsigned int* srow = Sums + ((size_t)pair * NROW + a) * NBINS;
    const unsigned int* crow = Sums + ((size_t)pair * NROW + AMP_N) * NBINS;   // counts
    const double inv_scale = 1.0 / (double)ASCALE;
    double m[NBINS], tot = 0.0;
    #pragma unroll
    for (int k = 0; k < NBINS; ++k) {
        double cnt = (double)crow[k];
        double denom = cnt > 1e-9 ? cnt : 1e-9;
        m[k] = ((double)srow[k] * inv_scale) / denom;
        tot += m[k];
    }
    double dt = tot > 1e-9 ? tot : 1e-9;
    double acc = 0.0;
    #pragma unroll
    for (int k = 0; k < NBINS; ++k) {
        double pr = m[k] / dt;
        acc += pr * log(pr + 1e-9);
    }
    const double lognb = log((double)NBINS);
    out[gid] = (float)((lognb + acc) / lognb);
}

extern "C" void kernel_launch(void* const* d_in, const int* in_sizes, int n_in,
                              void* d_out, int out_size, void* d_ws, size_t ws_size,
                              hipStream_t stream) {
    const float* x = (const float*)d_in[0];
    float* out = (float*)d_out;
    char* ws = (char*)d_ws;
    // workspace layout (~9.3 MB; all regions written before read each call):
    //   idx_buf:  16*50*1536 u8                      = 1,228,800 B @ 0
    //   ampu_buf: 16*30*1536 u32                     = 2,949,120 B @ 1,228,800
    //   Xp:       16 chunks * 16*768 complex double  = 3,145,728 B @ 4,177,920
    //   Xf:       16*768 complex double              =   196,608 B @ 7,323,648
    //   Sums:     800*31*18 u32                      = 1,785,600 B @ 7,520,256
    unsigned char* idx_buf = (unsigned char*)ws;
    unsigned int* ampu_buf = (unsigned int*)(ws + 1228800);
    double* Xp = (double*)(ws + 4177920);
    double* Xf = (double*)(ws + 7323648);
    unsigned int* Sums = (unsigned int*)(ws + 7520256);

    hipMemsetAsync(Sums, 0, (size_t)NBC * PHA_N * NROW * NBINS * 4, stream);
    dft_kernel<<<dim3(NBC, FMAX / 256, NCH), 256, 0, stream>>>(x, Xp);
    reduce_kernel<<<NBC * FMAX / 256, 256, 0, stream>>>(Xp, Xf);
    band_kernel<<<dim3(NBC, NBANDS, 2), 256, 0, stream>>>(Xf, idx_buf, ampu_buf);
    mi_part<<<dim3(NBC * PHA_N, QS), 256, 0, stream>>>(idx_buf, ampu_buf, Sums);
    mi_final<<<(NBC * PHA_N * AMP_N + 255) / 256, 256, 0, stream>>>(Sums, out);
}

// Round 10
// 146.519 us; speedup vs baseline: 1.0148x; 1.0148x over previous
//
#include <hip/hip_runtime.h>
#include <math.h>

#ifndef M_PI
#define M_PI 3.14159265358979323846
#endif

#define T 2048
#define EDGE 256
#define TT 1536            // trimmed timesteps
#define PHA_N 50
#define AMP_N 30
#define NBANDS 80
#define NBINS 18
#define NBC 16             // B*C = 2*8
#define FMAX 768           // forward DFT bins stored [0, FMAX); max needed bin = 634
#define NCH 16             // t-chunks for forward DFT
#define CHLEN (T / NCH)    // 128
#define QS 4               // t-quarters for mi_part
#define QT (TT / QS)       // 384
#define ASCALE 262144.0f   // 2^18 fixed-point scale for amp quantization

// Inclusive frequency-bin range [fl, fh] for a band, replicating the
// reference's float32 band edges vs exact quarter-Hz freq grid.
__device__ __forceinline__ void band_range(int band, int* fl, int* fh) {
    double lo, hi;
    if (band < PHA_N) {
        double mid = 2.0 + (double)band * (18.0 / 49.0);   // linspace(2,20,50)
        lo = (double)(float)(mid * 0.75);
        hi = (double)(float)(mid * 1.25);
    } else {
        int j = band - PHA_N;
        double mid = 60.0 + (double)j * (81.0 / 29.0);     // linspace(60,141,30)
        lo = (double)(float)(mid * 0.875);
        hi = (double)(float)(mid * 1.125);
    }
    int l = (int)ceil(lo * 4.0);     // freq = 0.25*f ; f >= 4*lo
    int h = (int)floor(hi * 4.0);    // f <= 4*hi
    if (l < 1) l = 1;
    if (h > FMAX - 1) h = FMAX - 1;
    *fl = l; *fh = h;
}

// Kernel A: chunked forward DFT partials. Two independent 64-step oscillator
// chains per thread; Xp layout ch-slowest for coalesced writes.
__global__ void dft_kernel(const float* __restrict__ x, double* __restrict__ Xp) {
    __shared__ float xs[CHLEN];
    const int bc = blockIdx.x;
    const int fb = blockIdx.y;
    const int ch = blockIdx.z;
    const int tid = threadIdx.x;
    const int t0 = ch * CHLEN;
    if (tid < CHLEN) xs[tid] = x[bc * T + t0 + tid];
    __syncthreads();
    const int f = fb * 256 + tid;
    const double om = 2.0 * M_PI / (double)T;
    double s, c;
    sincos(om * (double)(f & (T - 1)), &s, &c);
    const double wR = c, wI = -s;                       // e^{-i om f}
    double curR[2], curI[2], accR[2], accI[2];
    #pragma unroll
    for (int h = 0; h < 2; ++h) {
        sincos(om * (double)((f * (t0 + h * 64)) & (T - 1)), &s, &c);
        curR[h] = c; curI[h] = -s;                      // e^{-i om f (t0+64h)}
        accR[h] = 0.0; accI[h] = 0.0;
    }
    #pragma unroll 2
    for (int t = 0; t < 64; ++t) {
        #pragma unroll
        for (int h = 0; h < 2; ++h) {
            double v = (double)xs[t + h * 64];
            accR[h] += v * curR[h];
            accI[h] += v * curI[h];
            double nR = curR[h] * wR - curI[h] * wI;
            double nI = curR[h] * wI + curI[h] * wR;
            curR[h] = nR; curI[h] = nI;
        }
    }
    const size_t o = (size_t)((ch * NBC + bc) * FMAX + f) * 2;
    Xp[o + 0] = accR[0] + accR[1];
    Xp[o + 1] = accI[0] + accI[1];
}

// Kernel A2: reduce NCH chunk partials -> Xf[bc][f]. Coalesced.
__global__ void reduce_kernel(const double* __restrict__ Xp, double* __restrict__ Xf) {
    const int gid = blockIdx.x * 256 + threadIdx.x;   // 0..12287 = bc*FMAX+f
    double r = 0.0, im = 0.0;
    #pragma unroll
    for (int c = 0; c < NCH; ++c) {
        r  += Xp[((size_t)c * NBC * FMAX + gid) * 2 + 0];
        im += Xp[((size_t)c * NBC * FMAX + gid) * 2 + 1];
    }
    Xf[2 * gid + 0] = r;
    Xf[2 * gid + 1] = im;
}

// Kernel B: per (bc, band, t-half) analytic-signal synthesis.
// Phase bands fp64 (bin decision); amp bands fp32 -> u32 fixed-point.
// Twiddle setup: 2 per-thread sincos + 1 block-uniform sincos + ladder;
// e^{i om 256} = (sqrt2/2, sqrt2/2) is a compile-time constant (om*256 = pi/4).
#define NJ 3
#define SQRT2O2 0.70710678118654752440
__global__ void band_kernel(const double* __restrict__ Xf,
                            unsigned char* __restrict__ idx_buf,
                            unsigned int* __restrict__ ampu_buf) {
    __shared__ double sXr[164];
    __shared__ double sXi[164];
    const int bc = blockIdx.x;
    const int band = (NBANDS - 1) - blockIdx.y;   // biggest bands first
    const int half = blockIdx.z;
    const int tid = threadIdx.x;
    int fl, fh;
    band_range(band, &fl, &fh);
    const int nb = fh - fl + 1;
    const double om = 2.0 * M_PI / (double)T;
    const int t00 = tid + half * 768 + EDGE;      // time for j=0

    if (band < PHA_N) {
        // ---------- fp64 phase path ----------
        for (int i = tid; i < nb; i += 256) {
            sXr[i] = Xf[(size_t)(bc * FMAX + fl + i) * 2 + 0];
            sXi[i] = Xf[(size_t)(bc * FMAX + fl + i) * 2 + 1];
        }
        __syncthreads();
        double curR[NJ], curI[NJ], wR[NJ], wI[NJ], accR[NJ], accI[NJ];
        {
            double s, c;
            sincos(om * (double)((fl * t00) & (T - 1)), &s, &c);
            curR[0] = c; curI[0] = s;              // e^{+i om fl t00}
            sincos(om * (double)(t00 & (T - 1)), &s, &c);
            wR[0] = c; wI[0] = s;                  // e^{+i om t00}
            sincos(om * (double)((fl << 8) & (T - 1)), &s, &c);   // block-uniform
            const double scR = c, scI = s;         // e^{+i om fl 256}
            #pragma unroll
            for (int j = 1; j < NJ; ++j) {
                curR[j] = curR[j-1] * scR - curI[j-1] * scI;
                curI[j] = curR[j-1] * scI + curI[j-1] * scR;
                wR[j]  = wR[j-1] * SQRT2O2 - wI[j-1] * SQRT2O2;   // * e^{i pi/4}
                wI[j]  = wR[j-1] * SQRT2O2 + wI[j-1] * SQRT2O2;
            }
            #pragma unroll
            for (int j = 0; j < NJ; ++j) { accR[j] = 0.0; accI[j] = 0.0; }
        }
        #pragma unroll 2
        for (int i = 0; i < nb; ++i) {
            const double Xr = sXr[i], Xi = sXi[i];   // broadcast read
            #pragma unroll
            for (int j = 0; j < NJ; ++j) {
                accR[j] += Xr * curR[j] - Xi * curI[j];
                accI[j] += Xr * curI[j] + Xi * curR[j];
                double nR = curR[j] * wR[j] - curI[j] * wI[j];
                double nI = curR[j] * wI[j] + curI[j] * wR[j];
                curR[j] = nR; curI[j] = nI;
            }
        }
        const double width = 2.0 * M_PI / (double)NBINS;
        #pragma unroll
        for (int j = 0; j < NJ; ++j) {
            const int trel = tid + j * 256 + half * 768;
            double pha = atan2(accI[j], accR[j]);        // (-pi, pi]
            int b = (int)floor((pha + M_PI) / width);
            if (b < 0) b = 0;
            if (b > NBINS - 1) b = NBINS - 1;
            idx_buf[(size_t)(bc * PHA_N + band) * TT + trel] = (unsigned char)b;
        }
    } else {
        // ---------- fp32 amplitude path ----------
        float* fXr = (float*)sXr;
        float* fXi = (float*)sXi;
        for (int i = tid; i < nb; i += 256) {
            fXr[i] = (float)Xf[(size_t)(bc * FMAX + fl + i) * 2 + 0];
            fXi[i] = (float)Xf[(size_t)(bc * FMAX + fl + i) * 2 + 1];
        }
        __syncthreads();
        float curR[NJ], curI[NJ], wRf[NJ], wIf[NJ], accR[NJ], accI[NJ];
        {
            const float omf = (float)(2.0 * M_PI / (double)T);
            float s, c;
            sincosf(omf * (float)((fl * t00) & (T - 1)), &s, &c);
            curR[0] = c; curI[0] = s;
            sincosf(omf * (float)(t00 & (T - 1)), &s, &c);
            wRf[0] = c; wIf[0] = s;
            sincosf(omf * (float)((fl << 8) & (T - 1)), &s, &c);  // block-uniform
            const float scR = c, scI = s;
            const float swc = 0.70710678f;
            #pragma unroll
            for (int j = 1; j < NJ; ++j) {
                curR[j] = curR[j-1] * scR - curI[j-1] * scI;
                curI[j] = curR[j-1] * scI + curI[j-1] * scR;
                wRf[j] = wRf[j-1] * swc - wIf[j-1] * swc;
                wIf[j] = wRf[j-1] * swc + wIf[j-1] * swc;
            }
            #pragma unroll
            for (int j = 0; j < NJ; ++j) { accR[j] = 0.0f; accI[j] = 0.0f; }
        }
        #pragma unroll 2
        for (int i = 0; i < nb; ++i) {
            const float Xr = fXr[i], Xi = fXi[i];
            #pragma unroll
            for (int j = 0; j < NJ; ++j) {
                accR[j] += Xr * curR[j] - Xi * curI[j];
                accI[j] += Xr * curI[j] + Xi * curR[j];
                float nR = curR[j] * wRf[j] - curI[j] * wIf[j];
                float nI = curR[j] * wIf[j] + curI[j] * wRf[j];
                curR[j] = nR; curI[j] = nI;
            }
        }
        #pragma unroll
        for (int j = 0; j < NJ; ++j) {
            const int trel = tid + j * 256 + half * 768;
            float amp = sqrtf(accR[j] * accR[j] + accI[j] * accI[j]) * (2.0f / (float)T);
            ampu_buf[(size_t)(bc * AMP_N + (band - PHA_N)) * TT + trel] =
                (unsigned int)(amp * ASCALE + 0.5f);
        }
    }
}

// Kernel C1: HYBRID pipe split (R9 lesson: pure-LDS = 45us LDS-bound w/ VALU
// idle; R6 pure-select = 46us VALU-bound w/ LDS idle; pipes co-schedule
// across waves [m114]):
//   waves 0-1 (tid<128):   15 amp rows + counts row via private-row LDS RMW
//   waves 2-3 (tid 128..247): 15 amp rows via 18-register select tree (VALU)
// Wave-aligned split -> no intra-wave divergence between the two paths.
#define PK 19   // padded row stride
#define NROW 31 // rows 0..29 = amp bands, row 30 = counts
__global__ void mi_part(const unsigned char* __restrict__ idx_buf,
                        const unsigned int* __restrict__ ampu_buf,
                        unsigned int* __restrict__ Sums) {
    __shared__ unsigned int part[NROW * 8 * PK];  // [row][g][k], u32 fixed-point
    __shared__ unsigned int sidx_s[QT / 4];       // 96 packed idx words
    const int blk = blockIdx.x;               // bc*50 + p
    const int q = blockIdx.y;                 // t-quarter
    const int bc = blk / PHA_N;
    const int p = blk % PHA_N;
    const int tid = threadIdx.x;

    for (int i = tid; i < NROW * 8 * PK; i += 256) part[i] = 0u;
    if (tid < QT / 4)
        sidx_s[tid] = ((const unsigned int*)(idx_buf + (size_t)(bc * PHA_N + p) * TT + q * QT))[tid];
    __syncthreads();

    if (tid < 128) {
        // ---- LDS-RMW path: rows = amp 0..14 (r<15) and counts (r==15 -> row 30)
        const int r = tid >> 3;            // 0..15
        const int g = tid & 7;             // contiguous 48-t chunk
        const int rr = (r == 15) ? 30 : r;
        const uint4* ap = (const uint4*)(ampu_buf + (size_t)(bc * AMP_N + r) * TT + q * QT) + g * 12;
        unsigned int* myp = part + (rr * 8 + g) * PK;   // private row: no races
        #pragma unroll
        for (int it = 0; it < 12; ++it) {
            const unsigned int pk = sidx_s[g * 12 + it];   // LDS broadcast
            uint4 v;
            if (r < 15) v = ap[it];
            else { v.x = 1u; v.y = 1u; v.z = 1u; v.w = 1u; }
            myp[pk & 0xff]         += v.x;
            myp[(pk >> 8) & 0xff]  += v.y;
            myp[(pk >> 16) & 0xff] += v.z;
            myp[(pk >> 24) & 0xff] += v.w;
        }
    } else if (tid < 248) {
        // ---- register-select path: rows = amp 15..29
        const int v0 = tid - 128;          // 0..119
        const int rr = 15 + (v0 >> 3);     // amp band & part row, 15..29
        const int g = v0 & 7;
        const uint4* ap = (const uint4*)(ampu_buf + (size_t)(bc * AMP_N + rr) * TT + q * QT) + g * 12;
        unsigned int acc[NBINS];
        #pragma unroll
        for (int k = 0; k < NBINS; ++k) acc[k] = 0u;
        #pragma unroll
        for (int it = 0; it < 12; ++it) {
            const unsigned int pk = sidx_s[g * 12 + it];
            const uint4 v = ap[it];
            const int b0 = pk & 0xff, b1 = (pk >> 8) & 0xff;
            const int b2 = (pk >> 16) & 0xff, b3 = (pk >> 24) & 0xff;
            #pragma unroll
            for (int k = 0; k < NBINS; ++k) {
                acc[k] += (b0 == k) ? v.x : 0u;
                acc[k] += (b1 == k) ? v.y : 0u;
                acc[k] += (b2 == k) ? v.z : 0u;
                acc[k] += (b3 == k) ? v.w : 0u;
            }
        }
        unsigned int* myp = part + (rr * 8 + g) * PK;  // lanes contiguous: 2-way free
        #pragma unroll
        for (int k = 0; k < NBINS; ++k) myp[k] = acc[k];
    }
    __syncthreads();

    for (int i = tid; i < NROW * NBINS; i += 256) {
        const int row = i / NBINS, k = i - row * NBINS;
        unsigned int s = 0u;
        #pragma unroll
        for (int g = 0; g < 8; ++g) s += part[(row * 8 + g) * PK + k];
        atomicAdd(&Sums[((size_t)blk * NROW + row) * NBINS + k], s);   // global u32
    }
}

// Kernel C2: MI from Sums. One thread per (pair, amp band).
__global__ void mi_final(const unsigned int* __restrict__ Sums, float* __restrict__ out) {
    const int gid = blockIdx.x * 256 + threadIdx.x;
    if (gid >= NBC * PHA_N * AMP_N) return;
    const int pair = gid / AMP_N;
    const int a = gid - pair * AMP_N;
    const unsigned int* srow = Sums + ((size_t)pair * NROW + a) * NBINS;
    const unsigned int* crow = Sums + ((size_t)pair * NROW + AMP_N) * NBINS;   // counts
    const double inv_scale = 1.0 / (double)ASCALE;
    double m[NBINS], tot = 0.0;
    #pragma unroll
    for (int k = 0; k < NBINS; ++k) {
        double cnt = (double)crow[k];
        double denom = cnt > 1e-9 ? cnt : 1e-9;
        m[k] = ((double)srow[k] * inv_scale) / denom;
        tot += m[k];
    }
    double dt = tot > 1e-9 ? tot : 1e-9;
    double acc = 0.0;
    #pragma unroll
    for (int k = 0; k < NBINS; ++k) {
        double pr = m[k] / dt;
        acc += pr * log(pr + 1e-9);
    }
    const double lognb = log((double)NBINS);
    out[gid] = (float)((lognb + acc) / lognb);
}

extern "C" void kernel_launch(void* const* d_in, const int* in_sizes, int n_in,
                              void* d_out, int out_size, void* d_ws, size_t ws_size,
                              hipStream_t stream) {
    const float* x = (const float*)d_in[0];
    float* out = (float*)d_out;
    char* ws = (char*)d_ws;
    // workspace layout (~9.3 MB; all regions written before read each call):
    //   idx_buf:  16*50*1536 u8                      = 1,228,800 B @ 0
    //   ampu_buf: 16*30*1536 u32                     = 2,949,120 B @ 1,228,800
    //   Xp:       16 chunks * 16*768 complex double  = 3,145,728 B @ 4,177,920
    //   Xf:       16*768 complex double              =   196,608 B @ 7,323,648
    //   Sums:     800*31*18 u32                      = 1,785,600 B @ 7,520,256
    unsigned char* idx_buf = (unsigned char*)ws;
    unsigned int* ampu_buf = (unsigned int*)(ws + 1228800);
    double* Xp = (double*)(ws + 4177920);
    double* Xf = (double*)(ws + 7323648);
    unsigned int* Sums = (unsigned int*)(ws + 7520256);

    hipMemsetAsync(Sums, 0, (size_t)NBC * PHA_N * NROW * NBINS * 4, stream);
    dft_kernel<<<dim3(NBC, FMAX / 256, NCH), 256, 0, stream>>>(x, Xp);
    reduce_kernel<<<NBC * FMAX / 256, 256, 0, stream>>>(Xp, Xf);
    band_kernel<<<dim3(NBC, NBANDS, 2), 256, 0, stream>>>(Xf, idx_buf, ampu_buf);
    mi_part<<<dim3(NBC * PHA_N, QS), 256, 0, stream>>>(idx_buf, ampu_buf, Sums);
    mi_final<<<(NBC * PHA_N * AMP_N + 255) / 256, 256, 0, stream>>>(Sums, out);
}

// Round 11
// 129.229 us; speedup vs baseline: 1.1505x; 1.1338x over previous
//
#include <hip/hip_runtime.h>
#include <hip/hip_bf16.h>
#include <math.h>

#ifndef M_PI
#define M_PI 3.14159265358979323846
#endif

#define T 2048
#define EDGE 256
#define TT 1536            // trimmed timesteps
#define PHA_N 50
#define AMP_N 30
#define NBANDS 80
#define NBINS 18
#define NBC 16             // B*C = 2*8
#define FMAX 768           // forward DFT bins stored [0, FMAX); max needed bin = 634
#define NCH 16             // t-chunks for forward DFT
#define CHLEN (T / NCH)    // 128
#define MROWS 61           // 30 hi + 30 lo + 1 ones (counts)

typedef __attribute__((ext_vector_type(8))) short short8;     // 8 bf16 (4 VGPRs)
typedef __attribute__((ext_vector_type(16))) float float16;   // 32x32 C/D frag

// Inclusive frequency-bin range [fl, fh] for a band, replicating the
// reference's float32 band edges vs exact quarter-Hz freq grid.
__device__ __forceinline__ void band_range(int band, int* fl, int* fh) {
    double lo, hi;
    if (band < PHA_N) {
        double mid = 2.0 + (double)band * (18.0 / 49.0);   // linspace(2,20,50)
        lo = (double)(float)(mid * 0.75);
        hi = (double)(float)(mid * 1.25);
    } else {
        int j = band - PHA_N;
        double mid = 60.0 + (double)j * (81.0 / 29.0);     // linspace(60,141,30)
        lo = (double)(float)(mid * 0.875);
        hi = (double)(float)(mid * 1.125);
    }
    int l = (int)ceil(lo * 4.0);     // freq = 0.25*f ; f >= 4*lo
    int h = (int)floor(hi * 4.0);    // f <= 4*hi
    if (l < 1) l = 1;
    if (h > FMAX - 1) h = FMAX - 1;
    *fl = l; *fh = h;
}

// Kernel A: chunked forward DFT partials. Two independent 64-step oscillator
// chains per thread; Xp layout ch-slowest for coalesced writes.
__global__ void dft_kernel(const float* __restrict__ x, double* __restrict__ Xp) {
    __shared__ float xs[CHLEN];
    const int bc = blockIdx.x;
    const int fb = blockIdx.y;
    const int ch = blockIdx.z;
    const int tid = threadIdx.x;
    const int t0 = ch * CHLEN;
    if (tid < CHLEN) xs[tid] = x[bc * T + t0 + tid];
    __syncthreads();
    const int f = fb * 256 + tid;
    const double om = 2.0 * M_PI / (double)T;
    double s, c;
    sincos(om * (double)(f & (T - 1)), &s, &c);
    const double wR = c, wI = -s;                       // e^{-i om f}
    double curR[2], curI[2], accR[2], accI[2];
    #pragma unroll
    for (int h = 0; h < 2; ++h) {
        sincos(om * (double)((f * (t0 + h * 64)) & (T - 1)), &s, &c);
        curR[h] = c; curI[h] = -s;                      // e^{-i om f (t0+64h)}
        accR[h] = 0.0; accI[h] = 0.0;
    }
    #pragma unroll 2
    for (int t = 0; t < 64; ++t) {
        #pragma unroll
        for (int h = 0; h < 2; ++h) {
            double v = (double)xs[t + h * 64];
            accR[h] += v * curR[h];
            accI[h] += v * curI[h];
            double nR = curR[h] * wR - curI[h] * wI;
            double nI = curR[h] * wI + curI[h] * wR;
            curR[h] = nR; curI[h] = nI;
        }
    }
    const size_t o = (size_t)((ch * NBC + bc) * FMAX + f) * 2;
    Xp[o + 0] = accR[0] + accR[1];
    Xp[o + 1] = accI[0] + accI[1];
}

// Kernel A2: reduce NCH chunk partials -> Xf[bc][f]. Coalesced.
__global__ void reduce_kernel(const double* __restrict__ Xp, double* __restrict__ Xf) {
    const int gid = blockIdx.x * 256 + threadIdx.x;   // 0..12287 = bc*FMAX+f
    double r = 0.0, im = 0.0;
    #pragma unroll
    for (int c = 0; c < NCH; ++c) {
        r  += Xp[((size_t)c * NBC * FMAX + gid) * 2 + 0];
        im += Xp[((size_t)c * NBC * FMAX + gid) * 2 + 1];
    }
    Xf[2 * gid + 0] = r;
    Xf[2 * gid + 1] = im;
}

// Kernel B: per (bc, band, t-half) analytic-signal synthesis.
// Phase bands fp64 -> idx bytes; amp bands fp32 -> bf16 hi/lo rows of the
// A-matrix Abuf[bc][64][1536]: rows 0..29 = hi, 30..59 = lo, 60 = ones.
#define NJ 3
#define SQRT2O2 0.70710678118654752440
__global__ void band_kernel(const double* __restrict__ Xf,
                            unsigned char* __restrict__ idx_buf,
                            __hip_bfloat16* __restrict__ Abuf) {
    __shared__ double sXr[164];
    __shared__ double sXi[164];
    const int bc = blockIdx.x;
    const int band = (NBANDS - 1) - blockIdx.y;   // biggest bands first
    const int half = blockIdx.z;
    const int tid = threadIdx.x;
    int fl, fh;
    band_range(band, &fl, &fh);
    const int nb = fh - fl + 1;
    const double om = 2.0 * M_PI / (double)T;
    const int t00 = tid + half * 768 + EDGE;      // time for j=0

    if (band < PHA_N) {
        // ---------- fp64 phase path ----------
        for (int i = tid; i < nb; i += 256) {
            sXr[i] = Xf[(size_t)(bc * FMAX + fl + i) * 2 + 0];
            sXi[i] = Xf[(size_t)(bc * FMAX + fl + i) * 2 + 1];
        }
        __syncthreads();
        double curR[NJ], curI[NJ], wR[NJ], wI[NJ], accR[NJ], accI[NJ];
        {
            double s, c;
            sincos(om * (double)((fl * t00) & (T - 1)), &s, &c);
            curR[0] = c; curI[0] = s;              // e^{+i om fl t00}
            sincos(om * (double)(t00 & (T - 1)), &s, &c);
            wR[0] = c; wI[0] = s;                  // e^{+i om t00}
            sincos(om * (double)((fl << 8) & (T - 1)), &s, &c);   // block-uniform
            const double scR = c, scI = s;         // e^{+i om fl 256}
            #pragma unroll
            for (int j = 1; j < NJ; ++j) {
                curR[j] = curR[j-1] * scR - curI[j-1] * scI;
                curI[j] = curR[j-1] * scI + curI[j-1] * scR;
                wR[j]  = wR[j-1] * SQRT2O2 - wI[j-1] * SQRT2O2;   // * e^{i pi/4}
                wI[j]  = wR[j-1] * SQRT2O2 + wI[j-1] * SQRT2O2;
            }
            #pragma unroll
            for (int j = 0; j < NJ; ++j) { accR[j] = 0.0; accI[j] = 0.0; }
        }
        #pragma unroll 2
        for (int i = 0; i < nb; ++i) {
            const double Xr = sXr[i], Xi = sXi[i];   // broadcast read
            #pragma unroll
            for (int j = 0; j < NJ; ++j) {
                accR[j] += Xr * curR[j] - Xi * curI[j];
                accI[j] += Xr * curI[j] + Xi * curR[j];
                double nR = curR[j] * wR[j] - curI[j] * wI[j];
                double nI = curR[j] * wI[j] + curI[j] * wR[j];
                curR[j] = nR; curI[j] = nI;
            }
        }
        const double width = 2.0 * M_PI / (double)NBINS;
        #pragma unroll
        for (int j = 0; j < NJ; ++j) {
            const int trel = tid + j * 256 + half * 768;
            double pha = atan2(accI[j], accR[j]);        // (-pi, pi]
            int b = (int)floor((pha + M_PI) / width);
            if (b < 0) b = 0;
            if (b > NBINS - 1) b = NBINS - 1;
            idx_buf[(size_t)(bc * PHA_N + band) * TT + trel] = (unsigned char)b;
        }
    } else {
        // ---------- fp32 amplitude path ----------
        float* fXr = (float*)sXr;
        float* fXi = (float*)sXi;
        for (int i = tid; i < nb; i += 256) {
            fXr[i] = (float)Xf[(size_t)(bc * FMAX + fl + i) * 2 + 0];
            fXi[i] = (float)Xf[(size_t)(bc * FMAX + fl + i) * 2 + 1];
        }
        __syncthreads();
        float curR[NJ], curI[NJ], wRf[NJ], wIf[NJ], accR[NJ], accI[NJ];
        {
            const float omf = (float)(2.0 * M_PI / (double)T);
            float s, c;
            sincosf(omf * (float)((fl * t00) & (T - 1)), &s, &c);
            curR[0] = c; curI[0] = s;
            sincosf(omf * (float)(t00 & (T - 1)), &s, &c);
            wRf[0] = c; wIf[0] = s;
            sincosf(omf * (float)((fl << 8) & (T - 1)), &s, &c);  // block-uniform
            const float scR = c, scI = s;
            const float swc = 0.70710678f;
            #pragma unroll
            for (int j = 1; j < NJ; ++j) {
                curR[j] = curR[j-1] * scR - curI[j-1] * scI;
                curI[j] = curR[j-1] * scI + curI[j-1] * scR;
                wRf[j] = wRf[j-1] * swc - wIf[j-1] * swc;
                wIf[j] = wRf[j-1] * swc + wIf[j-1] * swc;
            }
            #pragma unroll
            for (int j = 0; j < NJ; ++j) { accR[j] = 0.0f; accI[j] = 0.0f; }
        }
        #pragma unroll 2
        for (int i = 0; i < nb; ++i) {
            const float Xr = fXr[i], Xi = fXi[i];
            #pragma unroll
            for (int j = 0; j < NJ; ++j) {
                accR[j] += Xr * curR[j] - Xi * curI[j];
                accI[j] += Xr * curI[j] + Xi * curR[j];
                float nR = curR[j] * wRf[j] - curI[j] * wIf[j];
                float nI = curR[j] * wIf[j] + curI[j] * wRf[j];
                curR[j] = nR; curI[j] = nI;
            }
        }
        const int a = band - PHA_N;
        #pragma unroll
        for (int j = 0; j < NJ; ++j) {
            const int trel = tid + j * 256 + half * 768;
            float amp = sqrtf(accR[j] * accR[j] + accI[j] * accI[j]) * (2.0f / (float)T);
            __hip_bfloat16 h = __float2bfloat16(amp);
            float rem = amp - __bfloat162float(h);
            Abuf[(size_t)(bc * 64 + a) * TT + trel] = h;                       // hi
            Abuf[(size_t)(bc * 64 + 30 + a) * TT + trel] = __float2bfloat16(rem); // lo
            if (band == NBANDS - 1)   // blockIdx.y==0: also fill the ones row
                Abuf[(size_t)(bc * 64 + 60) * TT + trel] = __float2bfloat16(1.0f);
        }
    }
}

// Kernel C1: bin-sum as MFMA matmul. Per (bc,p) block (800 blocks, 4 waves):
//   C[61x18] = A[61x1536] (bf16 hi/lo/ones) x Onehot[1536x18]
// B-fragments built IN REGISTERS from idx bytes (one-hot never materialized).
// mfma_f32_32x32x16_bf16: A[m=lane&31][k=(lane>>5)*8+j], B[k][n=lane&31],
// C/D row=(reg&3)+8*(reg>>2)+4*(lane>>5), col=lane&31 [C/D verified m74/m101].
// Waves: Mtile = wave>>1 (rows 32*Mtile..+31), khalf = wave&1 (768 k each).
// Scatter ladder lesson (R6-R9): all scatter forms plateau at ~45us; matmul
// form has ~5us of MFMA+build work.
__global__ void mi_part(const unsigned char* __restrict__ idx_buf,
                        const __hip_bfloat16* __restrict__ Abuf,
                        float* __restrict__ SumsF) {
    __shared__ unsigned int sidx_s[TT / 4];       // 384 packed idx words
    __shared__ float cpart[2][64][NBINS];         // per-khalf C partials
    const int blk = blockIdx.x;                   // bc*50 + p
    const int bc = blk / PHA_N;
    const int p = blk % PHA_N;
    const int tid = threadIdx.x;
    const int wave = tid >> 6;
    const int lane = tid & 63;
    const int Mtile = wave >> 1;
    const int khalf = wave & 1;

    for (int i = tid; i < TT / 4; i += 256)
        sidx_s[i] = ((const unsigned int*)(idx_buf + (size_t)(bc * PHA_N + p) * TT))[i];
    __syncthreads();

    const int n = lane & 31;
    const int kq = lane >> 5;                     // k-quad: 0 or 1 (8 k's each)
    const short8* arow = (const short8*)(Abuf + (size_t)(bc * 64 + Mtile * 32 + n) * TT
                                         + khalf * 768 + kq * 8);
    // arow[ks*2] advances 16 bf16 (one K-step) per ks*2 short8 units? No:
    // one short8 = 8 bf16; K-step stride = 16 bf16 = 2 short8 units.
    float16 acc = {0.0f};
    #pragma unroll 4
    for (int ks = 0; ks < 48; ++ks) {
        const short8 a = arow[ks * 2];
        const int w0 = khalf * 192 + ks * 4 + kq * 2;
        const unsigned int lo = sidx_s[w0];
        const unsigned int hi = sidx_s[w0 + 1];
        short8 b;
        b[0] = ((lo & 0xffu) == (unsigned)n) ? (short)0x3F80 : (short)0;
        b[1] = (((lo >> 8) & 0xffu) == (unsigned)n) ? (short)0x3F80 : (short)0;
        b[2] = (((lo >> 16) & 0xffu) == (unsigned)n) ? (short)0x3F80 : (short)0;
        b[3] = ((lo >> 24) == (unsigned)n) ? (short)0x3F80 : (short)0;
        b[4] = ((hi & 0xffu) == (unsigned)n) ? (short)0x3F80 : (short)0;
        b[5] = (((hi >> 8) & 0xffu) == (unsigned)n) ? (short)0x3F80 : (short)0;
        b[6] = (((hi >> 16) & 0xffu) == (unsigned)n) ? (short)0x3F80 : (short)0;
        b[7] = ((hi >> 24) == (unsigned)n) ? (short)0x3F80 : (short)0;
        acc = __builtin_amdgcn_mfma_f32_32x32x16_bf16(a, b, acc, 0, 0, 0);
    }

    // scatter C frag to LDS (cols >= NBINS discarded)
    if (n < NBINS) {
        #pragma unroll
        for (int r = 0; r < 16; ++r) {
            const int row = (r & 3) + 8 * (r >> 2) + 4 * kq;
            cpart[khalf][Mtile * 32 + row][n] = acc[r];
        }
    }
    __syncthreads();

    for (int i = tid; i < MROWS * NBINS; i += 256) {
        const int m = i / NBINS, k = i - m * NBINS;
        SumsF[(size_t)blk * MROWS * NBINS + i] = cpart[0][m][k] + cpart[1][m][k];
    }
}

// Kernel C2: MI from SumsF. One thread per (pair, amp band).
__global__ void mi_final(const float* __restrict__ SumsF, float* __restrict__ out) {
    const int gid = blockIdx.x * 256 + threadIdx.x;
    if (gid >= NBC * PHA_N * AMP_N) return;
    const int pair = gid / AMP_N;
    const int a = gid - pair * AMP_N;
    const float* base = SumsF + (size_t)pair * MROWS * NBINS;
    double m[NBINS], tot = 0.0;
    #pragma unroll
    for (int k = 0; k < NBINS; ++k) {
        double cnt = (double)base[60 * NBINS + k];                 // counts row
        double denom = cnt > 1e-9 ? cnt : 1e-9;
        double s = (double)base[a * NBINS + k] + (double)base[(30 + a) * NBINS + k];
        m[k] = s / denom;
        tot += m[k];
    }
    double dt = tot > 1e-9 ? tot : 1e-9;
    double acc = 0.0;
    #pragma unroll
    for (int k = 0; k < NBINS; ++k) {
        double pr = m[k] / dt;
        acc += pr * log(pr + 1e-9);
    }
    const double lognb = log((double)NBINS);
    out[gid] = (float)((lognb + acc) / lognb);
}

extern "C" void kernel_launch(void* const* d_in, const int* in_sizes, int n_in,
                              void* d_out, int out_size, void* d_ws, size_t ws_size,
                              hipStream_t stream) {
    const float* x = (const float*)d_in[0];
    float* out = (float*)d_out;
    char* ws = (char*)d_ws;
    // workspace layout (~7.9 MB; SumsF aliases the dead Xp region):
    //   idx_buf: 16*50*1536 u8                       = 1,228,800 B @ 0
    //   Abuf:    16*64*1536 bf16                     = 3,145,728 B @ 1,228,800
    //   Xp:      16 chunks * 16*768 complex double   = 3,145,728 B @ 4,374,528  (dead after reduce)
    //   SumsF:   800*61*18 f32                       = 3,513,600 B @ 4,374,528  (aliases Xp+)
    //   Xf:      16*768 complex double               =   196,608 B @ 7,888,128  (dead after band)
    unsigned char* idx_buf = (unsigned char*)ws;
    __hip_bfloat16* Abuf = (__hip_bfloat16*)(ws + 1228800);
    double* Xp = (double*)(ws + 4374528);
    float* SumsF = (float*)(ws + 4374528);
    double* Xf = (double*)(ws + 7888128);

    dft_kernel<<<dim3(NBC, FMAX / 256, NCH), 256, 0, stream>>>(x, Xp);
    reduce_kernel<<<NBC * FMAX / 256, 256, 0, stream>>>(Xp, Xf);
    band_kernel<<<dim3(NBC, NBANDS, 2), 256, 0, stream>>>(Xf, idx_buf, Abuf);
    mi_part<<<NBC * PHA_N, 256, 0, stream>>>(idx_buf, Abuf, SumsF);
    mi_final<<<(NBC * PHA_N * AMP_N + 255) / 256, 256, 0, stream>>>(SumsF, out);
}

// Round 12
// 125.554 us; speedup vs baseline: 1.1842x; 1.0293x over previous
//
#include <hip/hip_runtime.h>
#include <hip/hip_bf16.h>
#include <math.h>

#ifndef M_PI
#define M_PI 3.14159265358979323846
#endif

#define T 2048
#define EDGE 256
#define TT 1536            // trimmed timesteps
#define PHA_N 50
#define AMP_N 30
#define NBANDS 80
#define NBINS 18
#define NBC 16             // B*C = 2*8
#define FMAX 768           // forward DFT bins stored [0, FMAX); max needed bin = 634
#define NCH 16             // t-chunks for forward DFT
#define CHLEN (T / NCH)    // 128

typedef __attribute__((ext_vector_type(8))) short short8;     // 8 bf16 (4 VGPRs)
typedef __attribute__((ext_vector_type(16))) float float16;   // 32x32 C/D frag

// Inclusive frequency-bin range [fl, fh] for a band, replicating the
// reference's float32 band edges vs exact quarter-Hz freq grid.
__device__ __forceinline__ void band_range(int band, int* fl, int* fh) {
    double lo, hi;
    if (band < PHA_N) {
        double mid = 2.0 + (double)band * (18.0 / 49.0);   // linspace(2,20,50)
        lo = (double)(float)(mid * 0.75);
        hi = (double)(float)(mid * 1.25);
    } else {
        int j = band - PHA_N;
        double mid = 60.0 + (double)j * (81.0 / 29.0);     // linspace(60,141,30)
        lo = (double)(float)(mid * 0.875);
        hi = (double)(float)(mid * 1.125);
    }
    int l = (int)ceil(lo * 4.0);     // freq = 0.25*f ; f >= 4*lo
    int h = (int)floor(hi * 4.0);    // f <= 4*hi
    if (l < 1) l = 1;
    if (h > FMAX - 1) h = FMAX - 1;
    *fl = l; *fh = h;
}

// Kernel A: chunked forward DFT partials. Two independent 64-step oscillator
// chains per thread; Xp layout ch-slowest for coalesced writes.
__global__ void dft_kernel(const float* __restrict__ x, double* __restrict__ Xp) {
    __shared__ float xs[CHLEN];
    const int bc = blockIdx.x;
    const int fb = blockIdx.y;
    const int ch = blockIdx.z;
    const int tid = threadIdx.x;
    const int t0 = ch * CHLEN;
    if (tid < CHLEN) xs[tid] = x[bc * T + t0 + tid];
    __syncthreads();
    const int f = fb * 256 + tid;
    const double om = 2.0 * M_PI / (double)T;
    double s, c;
    sincos(om * (double)(f & (T - 1)), &s, &c);
    const double wR = c, wI = -s;                       // e^{-i om f}
    double curR[2], curI[2], accR[2], accI[2];
    #pragma unroll
    for (int h = 0; h < 2; ++h) {
        sincos(om * (double)((f * (t0 + h * 64)) & (T - 1)), &s, &c);
        curR[h] = c; curI[h] = -s;                      // e^{-i om f (t0+64h)}
        accR[h] = 0.0; accI[h] = 0.0;
    }
    #pragma unroll 2
    for (int t = 0; t < 64; ++t) {
        #pragma unroll
        for (int h = 0; h < 2; ++h) {
            double v = (double)xs[t + h * 64];
            accR[h] += v * curR[h];
            accI[h] += v * curI[h];
            double nR = curR[h] * wR - curI[h] * wI;
            double nI = curR[h] * wI + curI[h] * wR;
            curR[h] = nR; curI[h] = nI;
        }
    }
    const size_t o = (size_t)((ch * NBC + bc) * FMAX + f) * 2;
    Xp[o + 0] = accR[0] + accR[1];
    Xp[o + 1] = accI[0] + accI[1];
}

// Kernel B: per (bc, band, t-half) analytic-signal synthesis. Stages the band
// bins by summing the 16 L2-resident Xp chunk partials directly (reduce_kernel
// folded in). Phase bands fp64 -> idx bytes; amp bands fp32 -> bf16 hi/lo rows
// of A-matrix Abuf[bc][64][1536]: rows 0..29 hi, 30..59 lo, 60 ones.
#define NJ 3
#define SQRT2O2 0.70710678118654752440
__global__ void band_kernel(const double* __restrict__ Xp,
                            unsigned char* __restrict__ idx_buf,
                            __hip_bfloat16* __restrict__ Abuf) {
    __shared__ double sXr[164];
    __shared__ double sXi[164];
    const int bc = blockIdx.x;
    const int band = (NBANDS - 1) - blockIdx.y;   // biggest bands first
    const int half = blockIdx.z;
    const int tid = threadIdx.x;
    int fl, fh;
    band_range(band, &fl, &fh);
    const int nb = fh - fl + 1;
    const double om = 2.0 * M_PI / (double)T;
    const int t00 = tid + half * 768 + EDGE;      // time for j=0

    // stage band bins: sum the NCH chunk partials (Xp is 3 MB -> L2-resident)
    for (int i = tid; i < nb; i += 256) {
        const int f = fl + i;
        double r = 0.0, im = 0.0;
        #pragma unroll
        for (int c = 0; c < NCH; ++c) {
            const size_t o = (size_t)((c * NBC + bc) * FMAX + f) * 2;
            r += Xp[o]; im += Xp[o + 1];
        }
        sXr[i] = r; sXi[i] = im;
    }
    __syncthreads();

    if (band < PHA_N) {
        // ---------- fp64 phase path ----------
        double curR[NJ], curI[NJ], wR[NJ], wI[NJ], accR[NJ], accI[NJ];
        {
            double s, c;
            sincos(om * (double)((fl * t00) & (T - 1)), &s, &c);
            curR[0] = c; curI[0] = s;              // e^{+i om fl t00}
            sincos(om * (double)(t00 & (T - 1)), &s, &c);
            wR[0] = c; wI[0] = s;                  // e^{+i om t00}
            sincos(om * (double)((fl << 8) & (T - 1)), &s, &c);   // block-uniform
            const double scR = c, scI = s;         // e^{+i om fl 256}
            #pragma unroll
            for (int j = 1; j < NJ; ++j) {
                curR[j] = curR[j-1] * scR - curI[j-1] * scI;
                curI[j] = curR[j-1] * scI + curI[j-1] * scR;
                wR[j]  = wR[j-1] * SQRT2O2 - wI[j-1] * SQRT2O2;   // * e^{i pi/4}
                wI[j]  = wR[j-1] * SQRT2O2 + wI[j-1] * SQRT2O2;
            }
            #pragma unroll
            for (int j = 0; j < NJ; ++j) { accR[j] = 0.0; accI[j] = 0.0; }
        }
        #pragma unroll 2
        for (int i = 0; i < nb; ++i) {
            const double Xr = sXr[i], Xi = sXi[i];   // broadcast read
            #pragma unroll
            for (int j = 0; j < NJ; ++j) {
                accR[j] += Xr * curR[j] - Xi * curI[j];
                accI[j] += Xr * curI[j] + Xi * curR[j];
                double nR = curR[j] * wR[j] - curI[j] * wI[j];
                double nI = curR[j] * wI[j] + curI[j] * wR[j];
                curR[j] = nR; curI[j] = nI;
            }
        }
        const double width = 2.0 * M_PI / (double)NBINS;
        #pragma unroll
        for (int j = 0; j < NJ; ++j) {
            const int trel = tid + j * 256 + half * 768;
            double pha = atan2(accI[j], accR[j]);        // (-pi, pi]
            int b = (int)floor((pha + M_PI) / width);
            if (b < 0) b = 0;
            if (b > NBINS - 1) b = NBINS - 1;
            idx_buf[(size_t)(bc * PHA_N + band) * TT + trel] = (unsigned char)b;
        }
    } else {
        // ---------- fp32 amplitude path ----------
        float curR[NJ], curI[NJ], wRf[NJ], wIf[NJ], accR[NJ], accI[NJ];
        {
            const float omf = (float)(2.0 * M_PI / (double)T);
            float s, c;
            sincosf(omf * (float)((fl * t00) & (T - 1)), &s, &c);
            curR[0] = c; curI[0] = s;
            sincosf(omf * (float)(t00 & (T - 1)), &s, &c);
            wRf[0] = c; wIf[0] = s;
            sincosf(omf * (float)((fl << 8) & (T - 1)), &s, &c);  // block-uniform
            const float scR = c, scI = s;
            const float swc = 0.70710678f;
            #pragma unroll
            for (int j = 1; j < NJ; ++j) {
                curR[j] = curR[j-1] * scR - curI[j-1] * scI;
                curI[j] = curR[j-1] * scI + curI[j-1] * scR;
                wRf[j] = wRf[j-1] * swc - wIf[j-1] * swc;
                wIf[j] = wRf[j-1] * swc + wIf[j-1] * swc;
            }
            #pragma unroll
            for (int j = 0; j < NJ; ++j) { accR[j] = 0.0f; accI[j] = 0.0f; }
        }
        #pragma unroll 2
        for (int i = 0; i < nb; ++i) {
            const float Xr = (float)sXr[i], Xi = (float)sXi[i];
            #pragma unroll
            for (int j = 0; j < NJ; ++j) {
                accR[j] += Xr * curR[j] - Xi * curI[j];
                accI[j] += Xr * curI[j] + Xi * curR[j];
                float nR = curR[j] * wRf[j] - curI[j] * wIf[j];
                float nI = curR[j] * wIf[j] + curI[j] * wRf[j];
                curR[j] = nR; curI[j] = nI;
            }
        }
        const int a = band - PHA_N;
        #pragma unroll
        for (int j = 0; j < NJ; ++j) {
            const int trel = tid + j * 256 + half * 768;
            float amp = sqrtf(accR[j] * accR[j] + accI[j] * accI[j]) * (2.0f / (float)T);
            __hip_bfloat16 h = __float2bfloat16(amp);
            float rem = amp - __bfloat162float(h);
            Abuf[(size_t)(bc * 64 + a) * TT + trel] = h;                       // hi
            Abuf[(size_t)(bc * 64 + 30 + a) * TT + trel] = __float2bfloat16(rem); // lo
            if (band == NBANDS - 1)   // blockIdx.y==0: also fill the ones row
                Abuf[(size_t)(bc * 64 + 60) * TT + trel] = __float2bfloat16(1.0f);
        }
    }
}

// Kernel C: bin-sum as MFMA matmul + inline MI epilogue (mi_final folded in).
// Per (bc,p) block: C[61x18] = A[61x1536](bf16 hi/lo/ones) x Onehot[1536x18],
// B-fragments built in registers from idx bytes. Layouts verified (R10 passed
// bit-identical). MI tail: 30 threads compute out[blk*30+a] from LDS cpart.
__global__ void mi_kernel(const unsigned char* __restrict__ idx_buf,
                          const __hip_bfloat16* __restrict__ Abuf,
                          float* __restrict__ out) {
    __shared__ unsigned int sidx_s[TT / 4];       // 384 packed idx words
    __shared__ float cpart[2][64][NBINS];         // per-khalf C partials
    const int blk = blockIdx.x;                   // bc*50 + p
    const int bc = blk / PHA_N;
    const int p = blk % PHA_N;
    const int tid = threadIdx.x;
    const int wave = tid >> 6;
    const int lane = tid & 63;
    const int Mtile = wave >> 1;
    const int khalf = wave & 1;

    for (int i = tid; i < TT / 4; i += 256)
        sidx_s[i] = ((const unsigned int*)(idx_buf + (size_t)(bc * PHA_N + p) * TT))[i];
    __syncthreads();

    const int n = lane & 31;
    const int kq = lane >> 5;                     // k-quad: 0 or 1 (8 k's each)
    const short8* arow = (const short8*)(Abuf + (size_t)(bc * 64 + Mtile * 32 + n) * TT
                                         + khalf * 768 + kq * 8);
    float16 acc = {0.0f};
    #pragma unroll 4
    for (int ks = 0; ks < 48; ++ks) {
        const short8 a = arow[ks * 2];            // K-step stride = 16 bf16 = 2 short8
        const int w0 = khalf * 192 + ks * 4 + kq * 2;
        const unsigned int lo = sidx_s[w0];
        const unsigned int hi = sidx_s[w0 + 1];
        short8 b;
        b[0] = ((lo & 0xffu) == (unsigned)n) ? (short)0x3F80 : (short)0;
        b[1] = (((lo >> 8) & 0xffu) == (unsigned)n) ? (short)0x3F80 : (short)0;
        b[2] = (((lo >> 16) & 0xffu) == (unsigned)n) ? (short)0x3F80 : (short)0;
        b[3] = ((lo >> 24) == (unsigned)n) ? (short)0x3F80 : (short)0;
        b[4] = ((hi & 0xffu) == (unsigned)n) ? (short)0x3F80 : (short)0;
        b[5] = (((hi >> 8) & 0xffu) == (unsigned)n) ? (short)0x3F80 : (short)0;
        b[6] = (((hi >> 16) & 0xffu) == (unsigned)n) ? (short)0x3F80 : (short)0;
        b[7] = ((hi >> 24) == (unsigned)n) ? (short)0x3F80 : (short)0;
        acc = __builtin_amdgcn_mfma_f32_32x32x16_bf16(a, b, acc, 0, 0, 0);
    }

    // scatter C frag to LDS (cols >= NBINS discarded)
    if (n < NBINS) {
        #pragma unroll
        for (int r = 0; r < 16; ++r) {
            const int row = (r & 3) + 8 * (r >> 2) + 4 * kq;
            cpart[khalf][Mtile * 32 + row][n] = acc[r];
        }
    }
    __syncthreads();

    // MI epilogue: thread a < 30 computes out[blk*30 + a]
    if (tid < AMP_N) {
        const int a = tid;
        double m[NBINS], tot = 0.0;
        #pragma unroll
        for (int k = 0; k < NBINS; ++k) {
            double cnt = (double)(cpart[0][60][k] + cpart[1][60][k]);     // counts
            double denom = cnt > 1e-9 ? cnt : 1e-9;
            double s = (double)(cpart[0][a][k] + cpart[1][a][k])
                     + (double)(cpart[0][30 + a][k] + cpart[1][30 + a][k]);
            m[k] = s / denom;
            tot += m[k];
        }
        double dt = tot > 1e-9 ? tot : 1e-9;
        double accm = 0.0;
        #pragma unroll
        for (int k = 0; k < NBINS; ++k) {
            double pr = m[k] / dt;
            accm += pr * log(pr + 1e-9);
        }
        const double lognb = log((double)NBINS);
        out[(size_t)blk * AMP_N + a] = (float)((lognb + accm) / lognb);
    }
}

extern "C" void kernel_launch(void* const* d_in, const int* in_sizes, int n_in,
                              void* d_out, int out_size, void* d_ws, size_t ws_size,
                              hipStream_t stream) {
    const float* x = (const float*)d_in[0];
    float* out = (float*)d_out;
    char* ws = (char*)d_ws;
    // workspace layout (~7.5 MB; all regions written before read each call):
    //   idx_buf: 16*50*1536 u8                       = 1,228,800 B @ 0
    //   Abuf:    16*64*1536 bf16                     = 3,145,728 B @ 1,228,800
    //   Xp:      16 chunks * 16*768 complex double   = 3,145,728 B @ 4,374,528
    unsigned char* idx_buf = (unsigned char*)ws;
    __hip_bfloat16* Abuf = (__hip_bfloat16*)(ws + 1228800);
    double* Xp = (double*)(ws + 4374528);

    dft_kernel<<<dim3(NBC, FMAX / 256, NCH), 256, 0, stream>>>(x, Xp);
    band_kernel<<<dim3(NBC, NBANDS, 2), 256, 0, stream>>>(Xp, idx_buf, Abuf);
    mi_kernel<<<NBC * PHA_N, 256, 0, stream>>>(idx_buf, Abuf, out);
}

// Round 13
// 116.888 us; speedup vs baseline: 1.2720x; 1.0741x over previous
//
#include <hip/hip_runtime.h>
#include <hip/hip_bf16.h>
#include <math.h>

#ifndef M_PI
#define M_PI 3.14159265358979323846
#endif

#define T 2048
#define EDGE 256
#define TT 1536            // trimmed timesteps
#define PHA_N 50
#define AMP_N 30
#define NBANDS 80
#define NBINS 18
#define NBC 16             // B*C = 2*8
#define FMAX 768           // forward DFT bins stored [0, FMAX); max needed bin = 634
#define NCH 16             // t-chunks for forward DFT
#define CHLEN (T / NCH)    // 128

typedef __attribute__((ext_vector_type(8))) short short8;       // 8x16-bit
typedef __attribute__((ext_vector_type(8))) _Float16 half8;     // 8 f16 (4 VGPRs)
typedef __attribute__((ext_vector_type(16))) float float16;     // 32x32 C/D frag

// Inclusive frequency-bin range [fl, fh] for a band, replicating the
// reference's float32 band edges vs exact quarter-Hz freq grid.
__device__ __forceinline__ void band_range(int band, int* fl, int* fh) {
    double lo, hi;
    if (band < PHA_N) {
        double mid = 2.0 + (double)band * (18.0 / 49.0);   // linspace(2,20,50)
        lo = (double)(float)(mid * 0.75);
        hi = (double)(float)(mid * 1.25);
    } else {
        int j = band - PHA_N;
        double mid = 60.0 + (double)j * (81.0 / 29.0);     // linspace(60,141,30)
        lo = (double)(float)(mid * 0.875);
        hi = (double)(float)(mid * 1.125);
    }
    int l = (int)ceil(lo * 4.0);     // freq = 0.25*f ; f >= 4*lo
    int h = (int)floor(hi * 4.0);    // f <= 4*hi
    if (l < 1) l = 1;
    if (h > FMAX - 1) h = FMAX - 1;
    *fl = l; *fh = h;
}

// Kernel A: chunked forward DFT partials. Two independent 64-step oscillator
// chains per thread; Xp layout ch-slowest for coalesced writes.
__global__ void dft_kernel(const float* __restrict__ x, double* __restrict__ Xp) {
    __shared__ float xs[CHLEN];
    const int bc = blockIdx.x;
    const int fb = blockIdx.y;
    const int ch = blockIdx.z;
    const int tid = threadIdx.x;
    const int t0 = ch * CHLEN;
    if (tid < CHLEN) xs[tid] = x[bc * T + t0 + tid];
    __syncthreads();
    const int f = fb * 256 + tid;
    const double om = 2.0 * M_PI / (double)T;
    double s, c;
    sincos(om * (double)(f & (T - 1)), &s, &c);
    const double wR = c, wI = -s;                       // e^{-i om f}
    double curR[2], curI[2], accR[2], accI[2];
    #pragma unroll
    for (int h = 0; h < 2; ++h) {
        sincos(om * (double)((f * (t0 + h * 64)) & (T - 1)), &s, &c);
        curR[h] = c; curI[h] = -s;                      // e^{-i om f (t0+64h)}
        accR[h] = 0.0; accI[h] = 0.0;
    }
    #pragma unroll 2
    for (int t = 0; t < 64; ++t) {
        #pragma unroll
        for (int h = 0; h < 2; ++h) {
            double v = (double)xs[t + h * 64];
            accR[h] += v * curR[h];
            accI[h] += v * curI[h];
            double nR = curR[h] * wR - curI[h] * wI;
            double nI = curR[h] * wI + curI[h] * wR;
            curR[h] = nR; curI[h] = nI;
        }
    }
    const size_t o = (size_t)((ch * NBC + bc) * FMAX + f) * 2;
    Xp[o + 0] = accR[0] + accR[1];
    Xp[o + 1] = accI[0] + accI[1];
}

// Kernel B: per (bc, band, t-half) analytic-signal synthesis. Stages band bins
// by summing the 16 L2-resident Xp chunk partials (reduce folded in).
// Phase: fp64 osc -> atan2f bin (f32 atan2 err ~3e-7 rad vs 0.349 bin width).
// Amp: fp32 osc -> f16 A-matrix Abuf[bc][32][1536]: rows 0..29 amp, 30 ones,
// 31 dead (garbage OK: contributes only to discarded C row 31).
#define NJ 3
#define SQRT2O2 0.70710678118654752440
__global__ void band_kernel(const double* __restrict__ Xp,
                            unsigned char* __restrict__ idx_buf,
                            _Float16* __restrict__ Abuf) {
    __shared__ double sXr[164];
    __shared__ double sXi[164];
    const int bc = blockIdx.x;
    const int band = (NBANDS - 1) - blockIdx.y;   // biggest bands first
    const int half = blockIdx.z;
    const int tid = threadIdx.x;
    int fl, fh;
    band_range(band, &fl, &fh);
    const int nb = fh - fl + 1;
    const double om = 2.0 * M_PI / (double)T;
    const int t00 = tid + half * 768 + EDGE;      // time for j=0

    // stage band bins: sum the NCH chunk partials (Xp is 3 MB -> L2-resident)
    for (int i = tid; i < nb; i += 256) {
        const int f = fl + i;
        double r = 0.0, im = 0.0;
        #pragma unroll
        for (int c = 0; c < NCH; ++c) {
            const size_t o = (size_t)((c * NBC + bc) * FMAX + f) * 2;
            r += Xp[o]; im += Xp[o + 1];
        }
        sXr[i] = r; sXi[i] = im;
    }
    __syncthreads();

    if (band < PHA_N) {
        // ---------- fp64 phase path ----------
        double curR[NJ], curI[NJ], wR[NJ], wI[NJ], accR[NJ], accI[NJ];
        {
            double s, c;
            sincos(om * (double)((fl * t00) & (T - 1)), &s, &c);
            curR[0] = c; curI[0] = s;              // e^{+i om fl t00}
            sincos(om * (double)(t00 & (T - 1)), &s, &c);
            wR[0] = c; wI[0] = s;                  // e^{+i om t00}
            sincos(om * (double)((fl << 8) & (T - 1)), &s, &c);   // block-uniform
            const double scR = c, scI = s;         // e^{+i om fl 256}
            #pragma unroll
            for (int j = 1; j < NJ; ++j) {
                curR[j] = curR[j-1] * scR - curI[j-1] * scI;
                curI[j] = curR[j-1] * scI + curI[j-1] * scR;
                wR[j]  = wR[j-1] * SQRT2O2 - wI[j-1] * SQRT2O2;   // * e^{i pi/4}
                wI[j]  = wR[j-1] * SQRT2O2 + wI[j-1] * SQRT2O2;
            }
            #pragma unroll
            for (int j = 0; j < NJ; ++j) { accR[j] = 0.0; accI[j] = 0.0; }
        }
        #pragma unroll 2
        for (int i = 0; i < nb; ++i) {
            const double Xr = sXr[i], Xi = sXi[i];   // broadcast read
            #pragma unroll
            for (int j = 0; j < NJ; ++j) {
                accR[j] += Xr * curR[j] - Xi * curI[j];
                accI[j] += Xr * curI[j] + Xi * curR[j];
                double nR = curR[j] * wR[j] - curI[j] * wI[j];
                double nI = curR[j] * wI[j] + curI[j] * wR[j];
                curR[j] = nR; curI[j] = nI;
            }
        }
        const float widthf = (float)(2.0 * M_PI / (double)NBINS);
        const float pif = (float)M_PI;
        #pragma unroll
        for (int j = 0; j < NJ; ++j) {
            const int trel = tid + j * 256 + half * 768;
            float pha = atan2f((float)accI[j], (float)accR[j]);   // (-pi, pi]
            int b = (int)floorf((pha + pif) / widthf);
            if (b < 0) b = 0;
            if (b > NBINS - 1) b = NBINS - 1;
            idx_buf[(size_t)(bc * PHA_N + band) * TT + trel] = (unsigned char)b;
        }
    } else {
        // ---------- fp32 amplitude path ----------
        float curR[NJ], curI[NJ], wRf[NJ], wIf[NJ], accR[NJ], accI[NJ];
        {
            const float omf = (float)(2.0 * M_PI / (double)T);
            float s, c;
            sincosf(omf * (float)((fl * t00) & (T - 1)), &s, &c);
            curR[0] = c; curI[0] = s;
            sincosf(omf * (float)(t00 & (T - 1)), &s, &c);
            wRf[0] = c; wIf[0] = s;
            sincosf(omf * (float)((fl << 8) & (T - 1)), &s, &c);  // block-uniform
            const float scR = c, scI = s;
            const float swc = 0.70710678f;
            #pragma unroll
            for (int j = 1; j < NJ; ++j) {
                curR[j] = curR[j-1] * scR - curI[j-1] * scI;
                curI[j] = curR[j-1] * scI + curI[j-1] * scR;
                wRf[j] = wRf[j-1] * swc - wIf[j-1] * swc;
                wIf[j] = wRf[j-1] * swc + wIf[j-1] * swc;
            }
            #pragma unroll
            for (int j = 0; j < NJ; ++j) { accR[j] = 0.0f; accI[j] = 0.0f; }
        }
        #pragma unroll 2
        for (int i = 0; i < nb; ++i) {
            const float Xr = (float)sXr[i], Xi = (float)sXi[i];
            #pragma unroll
            for (int j = 0; j < NJ; ++j) {
                accR[j] += Xr * curR[j] - Xi * curI[j];
                accI[j] += Xr * curI[j] + Xi * curR[j];
                float nR = curR[j] * wRf[j] - curI[j] * wIf[j];
                float nI = curR[j] * wIf[j] + curI[j] * wRf[j];
                curR[j] = nR; curI[j] = nI;
            }
        }
        const int a = band - PHA_N;
        #pragma unroll
        for (int j = 0; j < NJ; ++j) {
            const int trel = tid + j * 256 + half * 768;
            float amp = sqrtf(accR[j] * accR[j] + accI[j] * accI[j]) * (2.0f / (float)T);
            Abuf[(size_t)(bc * 32 + a) * TT + trel] = (_Float16)amp;
            if (band == NBANDS - 1)   // blockIdx.y==0: also fill the ones row
                Abuf[(size_t)(bc * 32 + 30) * TT + trel] = (_Float16)1.0f;
        }
    }
}

// Kernel C: bin-sum as f16 MFMA matmul + inline MI epilogue.
// Per (bc,p) block: C[31x18] = A[31x1536](f16 amp+ones) x Onehot[1536x18].
// ONE M-tile (R12: f16 replaces bf16 hi/lo -> halves MFMA + B-build, the
// dominant VALU cost). 4 waves split K in quarters (384 each, 24 K-steps).
// B-frags built in registers from idx bytes (layouts verified R10/R11).
__global__ void mi_kernel(const unsigned char* __restrict__ idx_buf,
                          const _Float16* __restrict__ Abuf,
                          float* __restrict__ out) {
    __shared__ unsigned int sidx_s[TT / 4];       // 384 packed idx words
    __shared__ float cpart[4][32][NBINS];         // per-kquarter C partials
    const int blk = blockIdx.x;                   // bc*50 + p
    const int bc = blk / PHA_N;
    const int p = blk % PHA_N;
    const int tid = threadIdx.x;
    const int wave = tid >> 6;                    // k-quarter 0..3
    const int lane = tid & 63;

    for (int i = tid; i < TT / 4; i += 256)
        sidx_s[i] = ((const unsigned int*)(idx_buf + (size_t)(bc * PHA_N + p) * TT))[i];
    __syncthreads();

    const int n = lane & 31;                      // A row m == B col n == lane&31
    const int kq = lane >> 5;                     // k-quad: 0 or 1 (8 k's each)
    const half8* arow = (const half8*)(Abuf + (size_t)(bc * 32 + n) * TT
                                       + wave * 384 + kq * 8);
    float16 acc = {0.0f};
    #pragma unroll 4
    for (int ks = 0; ks < 24; ++ks) {
        const half8 a = arow[ks * 2];             // K-step stride = 16 f16 = 2 half8
        const int w0 = wave * 96 + ks * 4 + kq * 2;
        const unsigned int lo = sidx_s[w0];
        const unsigned int hi = sidx_s[w0 + 1];
        short8 bs;
        bs[0] = ((lo & 0xffu) == (unsigned)n) ? (short)0x3C00 : (short)0;   // f16 1.0
        bs[1] = (((lo >> 8) & 0xffu) == (unsigned)n) ? (short)0x3C00 : (short)0;
        bs[2] = (((lo >> 16) & 0xffu) == (unsigned)n) ? (short)0x3C00 : (short)0;
        bs[3] = ((lo >> 24) == (unsigned)n) ? (short)0x3C00 : (short)0;
        bs[4] = ((hi & 0xffu) == (unsigned)n) ? (short)0x3C00 : (short)0;
        bs[5] = (((hi >> 8) & 0xffu) == (unsigned)n) ? (short)0x3C00 : (short)0;
        bs[6] = (((hi >> 16) & 0xffu) == (unsigned)n) ? (short)0x3C00 : (short)0;
        bs[7] = ((hi >> 24) == (unsigned)n) ? (short)0x3C00 : (short)0;
        const half8 b = __builtin_bit_cast(half8, bs);
        acc = __builtin_amdgcn_mfma_f32_32x32x16_f16(a, b, acc, 0, 0, 0);
    }

    // scatter C frag to LDS (cols >= NBINS and row 31 discarded)
    if (n < NBINS) {
        #pragma unroll
        for (int r = 0; r < 16; ++r) {
            const int row = (r & 3) + 8 * (r >> 2) + 4 * kq;
            if (row < 31) cpart[wave][row][n] = acc[r];
        }
    }
    __syncthreads();

    // MI epilogue: thread a < 30 computes out[blk*30 + a]
    if (tid < AMP_N) {
        const int a = tid;
        double m[NBINS], tot = 0.0;
        #pragma unroll
        for (int k = 0; k < NBINS; ++k) {
            double cnt = (double)(cpart[0][30][k] + cpart[1][30][k]
                                + cpart[2][30][k] + cpart[3][30][k]);     // counts
            double denom = cnt > 1e-9 ? cnt : 1e-9;
            double s = (double)(cpart[0][a][k] + cpart[1][a][k]
                              + cpart[2][a][k] + cpart[3][a][k]);
            m[k] = s / denom;
            tot += m[k];
        }
        double dt = tot > 1e-9 ? tot : 1e-9;
        double accm = 0.0;
        #pragma unroll
        for (int k = 0; k < NBINS; ++k) {
            double pr = m[k] / dt;
            accm += pr * log(pr + 1e-9);
        }
        const double lognb = log((double)NBINS);
        out[(size_t)blk * AMP_N + a] = (float)((lognb + accm) / lognb);
    }
}

extern "C" void kernel_launch(void* const* d_in, const int* in_sizes, int n_in,
                              void* d_out, int out_size, void* d_ws, size_t ws_size,
                              hipStream_t stream) {
    const float* x = (const float*)d_in[0];
    float* out = (float*)d_out;
    char* ws = (char*)d_ws;
    // workspace layout (~5.9 MB; all regions written before read each call):
    //   idx_buf: 16*50*1536 u8                       = 1,228,800 B @ 0
    //   Abuf:    16*32*1536 f16                      = 1,572,864 B @ 1,228,800
    //   Xp:      16 chunks * 16*768 complex double   = 3,145,728 B @ 2,801,664
    unsigned char* idx_buf = (unsigned char*)ws;
    _Float16* Abuf = (_Float16*)(ws + 1228800);
    double* Xp = (double*)(ws + 2801664);

    dft_kernel<<<dim3(NBC, FMAX / 256, NCH), 256, 0, stream>>>(x, Xp);
    band_kernel<<<dim3(NBC, NBANDS, 2), 256, 0, stream>>>(Xp, idx_buf, Abuf);
    mi_kernel<<<NBC * PHA_N, 256, 0, stream>>>(idx_buf, Abuf, out);
}

// Round 14
// 114.497 us; speedup vs baseline: 1.2985x; 1.0209x over previous
//
#include <hip/hip_runtime.h>
#include <hip/hip_bf16.h>
#include <math.h>

#ifndef M_PI
#define M_PI 3.14159265358979323846
#endif

#define T 2048
#define EDGE 256
#define TT 1536            // trimmed timesteps
#define PHA_N 50
#define AMP_N 30
#define NBANDS 80
#define NBINS 18
#define NBC 16             // B*C = 2*8
#define FMAX 768           // forward DFT bins stored [0, FMAX); max needed bin = 634
#define NCH 16             // t-chunks for forward DFT
#define CHLEN (T / NCH)    // 128

typedef __attribute__((ext_vector_type(8))) short short8;       // 8x16-bit
typedef __attribute__((ext_vector_type(8))) _Float16 half8;     // 8 f16 (4 VGPRs)
typedef __attribute__((ext_vector_type(16))) float float16;     // 32x32 C/D frag

// Inclusive frequency-bin range [fl, fh] for a band, replicating the
// reference's float32 band edges vs exact quarter-Hz freq grid.
__device__ __forceinline__ void band_range(int band, int* fl, int* fh) {
    double lo, hi;
    if (band < PHA_N) {
        double mid = 2.0 + (double)band * (18.0 / 49.0);   // linspace(2,20,50)
        lo = (double)(float)(mid * 0.75);
        hi = (double)(float)(mid * 1.25);
    } else {
        int j = band - PHA_N;
        double mid = 60.0 + (double)j * (81.0 / 29.0);     // linspace(60,141,30)
        lo = (double)(float)(mid * 0.875);
        hi = (double)(float)(mid * 1.125);
    }
    int l = (int)ceil(lo * 4.0);     // freq = 0.25*f ; f >= 4*lo
    int h = (int)floor(hi * 4.0);    // f <= 4*hi
    if (l < 1) l = 1;
    if (h > FMAX - 1) h = FMAX - 1;
    *fl = l; *fh = h;
}

// Kernel A: chunked forward DFT partials (fp64 — feeds phase; kept fp64 to
// isolate the R13 fp32-phase-synthesis risk). Two independent 64-step chains.
__global__ void dft_kernel(const float* __restrict__ x, double* __restrict__ Xp) {
    __shared__ float xs[CHLEN];
    const int bc = blockIdx.x;
    const int fb = blockIdx.y;
    const int ch = blockIdx.z;
    const int tid = threadIdx.x;
    const int t0 = ch * CHLEN;
    if (tid < CHLEN) xs[tid] = x[bc * T + t0 + tid];
    __syncthreads();
    const int f = fb * 256 + tid;
    const double om = 2.0 * M_PI / (double)T;
    double s, c;
    sincos(om * (double)(f & (T - 1)), &s, &c);
    const double wR = c, wI = -s;                       // e^{-i om f}
    double curR[2], curI[2], accR[2], accI[2];
    #pragma unroll
    for (int h = 0; h < 2; ++h) {
        sincos(om * (double)((f * (t0 + h * 64)) & (T - 1)), &s, &c);
        curR[h] = c; curI[h] = -s;                      // e^{-i om f (t0+64h)}
        accR[h] = 0.0; accI[h] = 0.0;
    }
    #pragma unroll 2
    for (int t = 0; t < 64; ++t) {
        #pragma unroll
        for (int h = 0; h < 2; ++h) {
            double v = (double)xs[t + h * 64];
            accR[h] += v * curR[h];
            accI[h] += v * curI[h];
            double nR = curR[h] * wR - curI[h] * wI;
            double nI = curR[h] * wI + curI[h] * wR;
            curR[h] = nR; curI[h] = nI;
        }
    }
    const size_t o = (size_t)((ch * NBC + bc) * FMAX + f) * 2;
    Xp[o + 0] = accR[0] + accR[1];
    Xp[o + 1] = accI[0] + accI[1];
}

// Kernel B: per (bc, band, t-half) analytic-signal synthesis — fully fp32
// (R13: phase bands have nb<=41 recurrence steps -> fp32 osc error ~4e-6 rad
// vs 0.349 bin width; ref itself is complex64). Stages band bins by summing
// the 16 L2-resident Xp chunk partials. Phase -> idx byte (atan2f); amp ->
// f16 A-matrix Abuf[bc][32][1536]: rows 0..29 amp, 30 ones, 31 dead.
#define NJ 3
__global__ void band_kernel(const double* __restrict__ Xp,
                            unsigned char* __restrict__ idx_buf,
                            _Float16* __restrict__ Abuf) {
    __shared__ float sXr[164];
    __shared__ float sXi[164];
    const int bc = blockIdx.x;
    const int band = (NBANDS - 1) - blockIdx.y;   // biggest bands first
    const int half = blockIdx.z;
    const int tid = threadIdx.x;
    int fl, fh;
    band_range(band, &fl, &fh);
    const int nb = fh - fl + 1;
    const int t00 = tid + half * 768 + EDGE;      // time for j=0

    // stage band bins: sum the NCH chunk partials (Xp is 3 MB -> L2-resident)
    for (int i = tid; i < nb; i += 256) {
        const int f = fl + i;
        double r = 0.0, im = 0.0;
        #pragma unroll
        for (int c = 0; c < NCH; ++c) {
            const size_t o = (size_t)((c * NBC + bc) * FMAX + f) * 2;
            r += Xp[o]; im += Xp[o + 1];
        }
        sXr[i] = (float)r; sXi[i] = (float)im;
    }
    __syncthreads();

    // fp32 oscillator setup: 2 per-thread sincosf + 1 block-uniform + ladder
    float curR[NJ], curI[NJ], wR[NJ], wI[NJ], accR[NJ], accI[NJ];
    {
        const float omf = (float)(2.0 * M_PI / (double)T);
        float s, c;
        sincosf(omf * (float)((fl * t00) & (T - 1)), &s, &c);
        curR[0] = c; curI[0] = s;                 // e^{+i om fl t00}
        sincosf(omf * (float)(t00 & (T - 1)), &s, &c);
        wR[0] = c; wI[0] = s;                     // e^{+i om t00}
        sincosf(omf * (float)((fl << 8) & (T - 1)), &s, &c);   // block-uniform
        const float scR = c, scI = s;             // e^{+i om fl 256}
        const float swc = 0.70710678f;            // e^{+i om 256} = e^{i pi/4}
        #pragma unroll
        for (int j = 1; j < NJ; ++j) {
            curR[j] = curR[j-1] * scR - curI[j-1] * scI;
            curI[j] = curR[j-1] * scI + curI[j-1] * scR;
            wR[j] = wR[j-1] * swc - wI[j-1] * swc;
            wI[j] = wR[j-1] * swc + wI[j-1] * swc;
        }
        #pragma unroll
        for (int j = 0; j < NJ; ++j) { accR[j] = 0.0f; accI[j] = 0.0f; }
    }
    #pragma unroll 2
    for (int i = 0; i < nb; ++i) {
        const float Xr = sXr[i], Xi = sXi[i];     // broadcast read
        #pragma unroll
        for (int j = 0; j < NJ; ++j) {
            accR[j] += Xr * curR[j] - Xi * curI[j];
            accI[j] += Xr * curI[j] + Xi * curR[j];
            float nR = curR[j] * wR[j] - curI[j] * wI[j];
            float nI = curR[j] * wI[j] + curI[j] * wR[j];
            curR[j] = nR; curI[j] = nI;
        }
    }

    if (band < PHA_N) {
        const float widthf = (float)(2.0 * M_PI / (double)NBINS);
        const float pif = (float)M_PI;
        #pragma unroll
        for (int j = 0; j < NJ; ++j) {
            const int trel = tid + j * 256 + half * 768;
            float pha = atan2f(accI[j], accR[j]);        // (-pi, pi]
            int b = (int)floorf((pha + pif) / widthf);
            if (b < 0) b = 0;
            if (b > NBINS - 1) b = NBINS - 1;
            idx_buf[(size_t)(bc * PHA_N + band) * TT + trel] = (unsigned char)b;
        }
    } else {
        const int a = band - PHA_N;
        #pragma unroll
        for (int j = 0; j < NJ; ++j) {
            const int trel = tid + j * 256 + half * 768;
            float amp = sqrtf(accR[j] * accR[j] + accI[j] * accI[j]) * (2.0f / (float)T);
            Abuf[(size_t)(bc * 32 + a) * TT + trel] = (_Float16)amp;
            if (band == NBANDS - 1)   // blockIdx.y==0: also fill the ones row
                Abuf[(size_t)(bc * 32 + 30) * TT + trel] = (_Float16)1.0f;
        }
    }
}

// Kernel C: bin-sum as f16 MFMA matmul + inline MI epilogue.
// Per (bc,p) block: C[31x18] = A[31x1536](f16 amp+ones) x Onehot[1536x18].
// 4 waves split K in quarters (384 each, 24 K-steps). B-frags built in
// registers from idx bytes (layouts verified R10/R11; f16 verified R12).
__global__ void mi_kernel(const unsigned char* __restrict__ idx_buf,
                          const _Float16* __restrict__ Abuf,
                          float* __restrict__ out) {
    __shared__ unsigned int sidx_s[TT / 4];       // 384 packed idx words
    __shared__ float cpart[4][32][NBINS];         // per-kquarter C partials
    const int blk = blockIdx.x;                   // bc*50 + p
    const int bc = blk / PHA_N;
    const int p = blk % PHA_N;
    const int tid = threadIdx.x;
    const int wave = tid >> 6;                    // k-quarter 0..3
    const int lane = tid & 63;

    for (int i = tid; i < TT / 4; i += 256)
        sidx_s[i] = ((const unsigned int*)(idx_buf + (size_t)(bc * PHA_N + p) * TT))[i];
    __syncthreads();

    const int n = lane & 31;                      // A row m == B col n == lane&31
    const int kq = lane >> 5;                     // k-quad: 0 or 1 (8 k's each)
    const half8* arow = (const half8*)(Abuf + (size_t)(bc * 32 + n) * TT
                                       + wave * 384 + kq * 8);
    float16 acc = {0.0f};
    #pragma unroll 4
    for (int ks = 0; ks < 24; ++ks) {
        const half8 a = arow[ks * 2];             // K-step stride = 16 f16 = 2 half8
        const int w0 = wave * 96 + ks * 4 + kq * 2;
        const unsigned int lo = sidx_s[w0];
        const unsigned int hi = sidx_s[w0 + 1];
        short8 bs;
        bs[0] = ((lo & 0xffu) == (unsigned)n) ? (short)0x3C00 : (short)0;   // f16 1.0
        bs[1] = (((lo >> 8) & 0xffu) == (unsigned)n) ? (short)0x3C00 : (short)0;
        bs[2] = (((lo >> 16) & 0xffu) == (unsigned)n) ? (short)0x3C00 : (short)0;
        bs[3] = ((lo >> 24) == (unsigned)n) ? (short)0x3C00 : (short)0;
        bs[4] = ((hi & 0xffu) == (unsigned)n) ? (short)0x3C00 : (short)0;
        bs[5] = (((hi >> 8) & 0xffu) == (unsigned)n) ? (short)0x3C00 : (short)0;
        bs[6] = (((hi >> 16) & 0xffu) == (unsigned)n) ? (short)0x3C00 : (short)0;
        bs[7] = ((hi >> 24) == (unsigned)n) ? (short)0x3C00 : (short)0;
        const half8 b = __builtin_bit_cast(half8, bs);
        acc = __builtin_amdgcn_mfma_f32_32x32x16_f16(a, b, acc, 0, 0, 0);
    }

    // scatter C frag to LDS (cols >= NBINS and row 31 discarded)
    if (n < NBINS) {
        #pragma unroll
        for (int r = 0; r < 16; ++r) {
            const int row = (r & 3) + 8 * (r >> 2) + 4 * kq;
            if (row < 31) cpart[wave][row][n] = acc[r];
        }
    }
    __syncthreads();

    // MI epilogue: thread a < 30 computes out[blk*30 + a]
    if (tid < AMP_N) {
        const int a = tid;
        double m[NBINS], tot = 0.0;
        #pragma unroll
        for (int k = 0; k < NBINS; ++k) {
            double cnt = (double)(cpart[0][30][k] + cpart[1][30][k]
                                + cpart[2][30][k] + cpart[3][30][k]);     // counts
            double denom = cnt > 1e-9 ? cnt : 1e-9;
            double s = (double)(cpart[0][a][k] + cpart[1][a][k]
                              + cpart[2][a][k] + cpart[3][a][k]);
            m[k] = s / denom;
            tot += m[k];
        }
        double dt = tot > 1e-9 ? tot : 1e-9;
        double accm = 0.0;
        #pragma unroll
        for (int k = 0; k < NBINS; ++k) {
            double pr = m[k] / dt;
            accm += pr * log(pr + 1e-9);
        }
        const double lognb = log((double)NBINS);
        out[(size_t)blk * AMP_N + a] = (float)((lognb + accm) / lognb);
    }
}

extern "C" void kernel_launch(void* const* d_in, const int* in_sizes, int n_in,
                              void* d_out, int out_size, void* d_ws, size_t ws_size,
                              hipStream_t stream) {
    const float* x = (const float*)d_in[0];
    float* out = (float*)d_out;
    char* ws = (char*)d_ws;
    // workspace layout (~5.9 MB; all regions written before read each call):
    //   idx_buf: 16*50*1536 u8                       = 1,228,800 B @ 0
    //   Abuf:    16*32*1536 f16                      = 1,572,864 B @ 1,228,800
    //   Xp:      16 chunks * 16*768 complex double   = 3,145,728 B @ 2,801,664
    unsigned char* idx_buf = (unsigned char*)ws;
    _Float16* Abuf = (_Float16*)(ws + 1228800);
    double* Xp = (double*)(ws + 2801664);

    dft_kernel<<<dim3(NBC, FMAX / 256, NCH), 256, 0, stream>>>(x, Xp);
    band_kernel<<<dim3(NBC, NBANDS, 2), 256, 0, stream>>>(Xp, idx_buf, Abuf);
    mi_kernel<<<NBC * PHA_N, 256, 0, stream>>>(idx_buf, Abuf, out);
}